// Round 6
// baseline (289.252 us; speedup 1.0000x reference)
//
#include <hip/hip_runtime.h>
#include <hip/hip_bf16.h>

// Problem constants (fixed by the reference):
//   img [8192,1024] f32, txt [8192,1024] f32, both l2-normalized
//   si=st=4, t=16, tts=1, DENOM=2  -> out[bi][bt] = (right+left)/128
//   out [2048,2048] f32
#define N_ROWS 8192
#define DIM    1024
#define BOUT   2048
#define BM 128
#define BN 128
#define BK 32
#define LDSBUF 8192   // u16 elements per double-buffer half (A 4096 + B 4096)

typedef unsigned short u16;
typedef __attribute__((ext_vector_type(4))) unsigned short u16x4;
typedef __attribute__((ext_vector_type(4))) unsigned int   u32x4;  // 16 B staging reg
typedef __attribute__((ext_vector_type(4))) float f32v4;     // nontemporal-ok fp32x4
typedef __attribute__((ext_vector_type(8))) short short8;    // 8 bf16 MFMA A/B frag
typedef __attribute__((ext_vector_type(16))) float f32x16;   // 32x32 MFMA C/D frag

// fp32 -> bf16 round-to-nearest-even
__device__ __forceinline__ u16 f2bf(float f) {
  unsigned u = __float_as_uint(f);
  u += 0x7fffu + ((u >> 16) & 1u);
  return (u16)(u >> 16);
}

__global__ void cast_kernel(const float* __restrict__ a, const float* __restrict__ b,
                            u16* __restrict__ oa, u16* __restrict__ ob) {
  const size_t i = ((size_t)blockIdx.x * 256 + threadIdx.x) * 4;
  f32v4 va = __builtin_nontemporal_load(reinterpret_cast<const f32v4*>(a + i));
  f32v4 vb = __builtin_nontemporal_load(reinterpret_cast<const f32v4*>(b + i));
  u16x4 ua, ub;
  ua[0] = f2bf(va.x); ua[1] = f2bf(va.y); ua[2] = f2bf(va.z); ua[3] = f2bf(va.w);
  ub[0] = f2bf(vb.x); ub[1] = f2bf(vb.y); ub[2] = f2bf(vb.z); ub[3] = f2bf(vb.w);
  // cacheable stores: gemm rereads these from L2/L3
  *reinterpret_cast<u16x4*>(oa + i) = ua;
  *reinterpret_cast<u16x4*>(ob + i) = ub;
}

// NT GEMM (dist = A.B^T) + fused smooth-chamfer 4x4-block epilogue.
// Software-pipelined K-loop (register prefetch distance 1, LDS double buffer,
// raw lgkm-only barrier): load k+1 -> compute k -> ds_write k+1 -> barrier.
// The vmcnt wait for the prefetch sits AFTER compute (data dep at ds_write),
// so L2 latency is overlapped instead of drained at a __syncthreads.
__global__ __launch_bounds__(256) void gemm_chamfer(
    const u16* __restrict__ A, const u16* __restrict__ B, float* __restrict__ out) {
  __shared__ __align__(16) u16 lds[2 * LDSBUF];   // 32 KiB

  const int tid  = threadIdx.x;
  const int lane = tid & 63;
  const int wave = tid >> 6;
  const int wm = wave & 1;          // wave row (64 rows)
  const int wn = wave >> 1;         // wave col (64 cols)
  const int bm0 = blockIdx.x * BM;
  const int bn0 = blockIdx.y * BN;

  // staging map (R3/R4-verified): thread t -> row r = t>>2 (and r+64),
  // LDS slot t&3, global chunk (t&3)^((r>>1)&3)  [swizzle for reader banks]
  const int ldrow = tid >> 2;
  const int ldk   = (((tid & 3) ^ ((tid >> 3) & 3)) * 8);
  const u16* aSrc = A + (size_t)(bm0 + ldrow) * DIM + ldk;
  const u16* bSrc = B + (size_t)(bn0 + ldrow) * DIM + ldk;
  const size_t half = (size_t)64 * DIM;
  const int woff = tid * 8;         // this thread's 16 B slot within a region

  f32x16 acc[2][2] = {};

  const int lm5 = lane & 31;   // A/B row within 32-tile (= C col)
  const int h   = lane >> 5;   // k-half selector; C row offset
  const int sw = (lm5 >> 1) & 3;
  const int slot0 = ((h)     ^ sw) * 8;   // k-step 0 chunk = h
  const int slot1 = ((h | 2) ^ sw) * 8;   // k-step 1 chunk = h+2
  int rowOffA[2], rowOffB[2];
#pragma unroll
  for (int i = 0; i < 2; ++i) {
    rowOffA[i] = (wm * 64 + i * 32 + lm5) * BK;
    rowOffB[i] = (wn * 64 + i * 32 + lm5) * BK;
  }

  // ---- prologue: stage k=0 into buffer 0 ----
  u32x4 ra0 = *reinterpret_cast<const u32x4*>(aSrc);
  u32x4 ra1 = *reinterpret_cast<const u32x4*>(aSrc + half);
  u32x4 rb0 = *reinterpret_cast<const u32x4*>(bSrc);
  u32x4 rb1 = *reinterpret_cast<const u32x4*>(bSrc + half);
  {
    u16* a = lds + woff;
    u16* b = lds + 4096 + woff;
    *reinterpret_cast<u32x4*>(a)        = ra0;
    *reinterpret_cast<u32x4*>(a + 2048) = ra1;
    *reinterpret_cast<u32x4*>(b)        = rb0;
    *reinterpret_cast<u32x4*>(b + 2048) = rb1;
  }
  asm volatile("s_waitcnt lgkmcnt(0)\n\ts_barrier" ::: "memory");

#pragma unroll 2
  for (int k = 0, p = 0; k < DIM; k += BK, p ^= 1) {
    const bool more = (k + BK < DIM);
    if (more) {   // prefetch next tile into registers (no wait)
      ra0 = *reinterpret_cast<const u32x4*>(aSrc + k + BK);
      ra1 = *reinterpret_cast<const u32x4*>(aSrc + k + BK + half);
      rb0 = *reinterpret_cast<const u32x4*>(bSrc + k + BK);
      rb1 = *reinterpret_cast<const u32x4*>(bSrc + k + BK + half);
    }

    const u16* curA = lds + p * LDSBUF;
    const u16* curB = curA + 4096;

    short8 af[2], bfv[2];
#pragma unroll
    for (int mt = 0; mt < 2; ++mt) {
      af[mt]  = *reinterpret_cast<const short8*>(&curA[rowOffA[mt] + slot0]);
      bfv[mt] = *reinterpret_cast<const short8*>(&curB[rowOffB[mt] + slot0]);
    }
#pragma unroll
    for (int mt = 0; mt < 2; ++mt)
#pragma unroll
      for (int nt = 0; nt < 2; ++nt)
        acc[mt][nt] = __builtin_amdgcn_mfma_f32_32x32x16_bf16(af[mt], bfv[nt], acc[mt][nt], 0, 0, 0);

#pragma unroll
    for (int mt = 0; mt < 2; ++mt) {
      af[mt]  = *reinterpret_cast<const short8*>(&curA[rowOffA[mt] + slot1]);
      bfv[mt] = *reinterpret_cast<const short8*>(&curB[rowOffB[mt] + slot1]);
    }
#pragma unroll
    for (int mt = 0; mt < 2; ++mt)
#pragma unroll
      for (int nt = 0; nt < 2; ++nt)
        acc[mt][nt] = __builtin_amdgcn_mfma_f32_32x32x16_bf16(af[mt], bfv[nt], acc[mt][nt], 0, 0, 0);

    if (more) {   // write prefetched tile into the other buffer
      u16* a = lds + (p ^ 1) * LDSBUF + woff;
      u16* b = lds + (p ^ 1) * LDSBUF + 4096 + woff;
      *reinterpret_cast<u32x4*>(a)        = ra0;
      *reinterpret_cast<u32x4*>(a + 2048) = ra1;
      *reinterpret_cast<u32x4*>(b)        = rb0;
      *reinterpret_cast<u32x4*>(b + 2048) = rb1;
    }
    // raw barrier: my ds_writes retired (lgkm), everyone's ds_reads were
    // already consumed by MFMAs. No vmcnt drain -> prefetch stays in flight.
    asm volatile("s_waitcnt lgkmcnt(0)\n\ts_barrier" ::: "memory");
  }

  // Fused epilogue. 32x32 C layout (m74/m101-verified):
  //   col = lane&31, row = (reg&3) + 8*(reg>>2) + 4*(lane>>5).
  // Each 4-reg group g = one 4-aligned img-set of column lane&31.
#pragma unroll
  for (int mt = 0; mt < 2; ++mt) {
#pragma unroll
    for (int nt = 0; nt < 2; ++nt) {
#pragma unroll
      for (int g = 0; g < 4; ++g) {
        float e0 = __expf(16.0f * acc[mt][nt][4 * g + 0]);
        float e1 = __expf(16.0f * acc[mt][nt][4 * g + 1]);
        float e2 = __expf(16.0f * acc[mt][nt][4 * g + 2]);
        float e3 = __expf(16.0f * acc[mt][nt][4 * g + 3]);
        float l = __logf(e0 + e1 + e2 + e3);          // left partial (per column)
        e0 += __shfl_xor(e0, 1); e0 += __shfl_xor(e0, 2);
        e1 += __shfl_xor(e1, 1); e1 += __shfl_xor(e1, 2);
        e2 += __shfl_xor(e2, 1); e2 += __shfl_xor(e2, 2);
        e3 += __shfl_xor(e3, 1); e3 += __shfl_xor(e3, 2);
        float r = __logf(e0) + __logf(e1) + __logf(e2) + __logf(e3);
        l += __shfl_xor(l, 1); l += __shfl_xor(l, 2);
        if ((lane & 3) == 0) {
          const int obi = (bm0 + wm * 64 + mt * 32 + 8 * g + 4 * h) >> 2;
          const int obt = ((bn0 + wn * 64 + nt * 32) >> 2) + (lm5 >> 2);
          out[(size_t)obi * BOUT + obt] = (r + l) * 0.0078125f;  // /128
        }
      }
    }
  }
}

extern "C" void kernel_launch(void* const* d_in, const int* in_sizes, int n_in,
                              void* d_out, int out_size, void* d_ws, size_t ws_size,
                              hipStream_t stream) {
  const float* img = (const float*)d_in[0];
  const float* txt = (const float*)d_in[1];
  float* out = (float*)d_out;
  u16* bA = (u16*)d_ws;                       // 16 MiB
  u16* bB = bA + (size_t)N_ROWS * DIM;        // 16 MiB

  const int nPer = N_ROWS * DIM;              // 8388608 per input
  cast_kernel<<<dim3(nPer / (256 * 4)), dim3(256), 0, stream>>>(img, txt, bA, bB);

  dim3 ggrid(N_ROWS / BM, N_ROWS / BN);       // 64 x 64 = 4096 blocks
  gemm_chamfer<<<ggrid, dim3(256), 0, stream>>>(bA, bB, out);
}